// Round 8
// baseline (187.672 us; speedup 1.0000x reference)
//
#include <hip/hip_runtime.h>

// Problem constants
#define BATCH 2
#define SEQ   2048
#define DIM   1024
#define NHEAD 16
#define HD    64
#define BH    (BATCH * NHEAD)   // 32
#define SCALE 0.125f            // 64^-0.5
#define LOG2E 1.44269504f
#define NTK   16                // k-tiles of 64 keys per key-half (1024/64)

typedef __attribute__((ext_vector_type(8))) short short8;
typedef __attribute__((ext_vector_type(4))) short short4v;
typedef __attribute__((ext_vector_type(4))) float f32x4;
typedef __attribute__((ext_vector_type(16))) float f32x16;
typedef __attribute__((ext_vector_type(2))) unsigned int uint2v;

#define MFMA16(a, b, c) __builtin_amdgcn_mfma_f32_16x16x32_bf16(a, b, c, 0, 0, 0)
#define MFMA32(a, b, c) __builtin_amdgcn_mfma_f32_32x32x16_bf16(a, b, c, 0, 0, 0)

__device__ __forceinline__ ushort f2bf(float f) {
    union { float f; unsigned u; } v;
    v.f = f;
    unsigned r = (v.u + 0x7FFF + ((v.u >> 16) & 1)) >> 16;   // RNE
    return (ushort)r;
}

__device__ __forceinline__ uint4 ld8f_bf16(const float* p) {
    float4 f0 = *(const float4*)p;
    float4 f1 = *(const float4*)(p + 4);
    union { ushort us[8]; uint4 v; } u;
    u.us[0] = f2bf(f0.x); u.us[1] = f2bf(f0.y);
    u.us[2] = f2bf(f0.z); u.us[3] = f2bf(f0.w);
    u.us[4] = f2bf(f1.x); u.us[5] = f2bf(f1.y);
    u.us[6] = f2bf(f1.z); u.us[7] = f2bf(f1.w);
    return u.v;
}

// async global->LDS, 16B/lane: lane i's 16B lands at l + i*16 (l wave-uniform)
__device__ __forceinline__ void gl_lds16(const ushort* g, ushort* l) {
    __builtin_amdgcn_global_load_lds(
        (const __attribute__((address_space(1))) unsigned int*)g,
        (__attribute__((address_space(3))) unsigned int*)l,
        16, 0, 0);
}

// two ds_read_b64 halves of one MFMA operand.  Content is PRE-SWAPPED per row
// parity (gemm MODE 0 epilogue), so the parity-offset address pair (a1, a1^4)
// yields true (lo,hi) order with ZERO fixup VALU; 16 distinct 8B-groups across
// 32 lanes per read -> 2-way bank aliasing = free.
__device__ __forceinline__ short8 ld_op(const ushort* base, int a1) {
    union { short4v h[2]; short8 v; } u;
    u.h[0] = *(const short4v*)&base[a1];
    u.h[1] = *(const short4v*)&base[a1 ^ 4];
    return u.v;
}

// ---------------------------------------------------------------------------
// fp32 -> bf16 bulk convert: x | qkv_w | proj_w
// ---------------------------------------------------------------------------
#define N_X  (BATCH * SEQ * DIM)       // 4194304
#define N_QW (3 * DIM * DIM)           // 3145728
#define N_PW (DIM * DIM)               // 1048576

__global__ __launch_bounds__(256) void cvt_kernel(
    const float* __restrict__ x, const float* __restrict__ qw,
    const float* __restrict__ pw, ushort* __restrict__ xb,
    ushort* __restrict__ qwb, ushort* __restrict__ pwb)
{
    const int i = (blockIdx.x * 256 + threadIdx.x) * 8;
    if (i < N_X)  *(uint4*)(xb  + i) = ld8f_bf16(x  + i);
    if (i < N_QW) *(uint4*)(qwb + i) = ld8f_bf16(qw + i);
    if (i < N_PW) *(uint4*)(pwb + i) = ld8f_bf16(pw + i);
}

// ---------------------------------------------------------------------------
// GEMM: C[M,N] = A[M,K] @ W[N,K]^T + bias[N], A/W bf16, bias fp32.
// 1-D grid with bijective XCD y-slab swizzle (grid%8==0): each XCD owns a
// contiguous m-row slab -> A-panels L2-resident per XCD.
// MODE 0: scatter bf16 -> Q (pre-scaled by SCALE*LOG2E), K as [BH][SEQ][HD],
//         V transposed as [BH][HD][SEQ].  K and V stored with 8B-half
//         PRE-SWAP per row parity (K: d^=4 if nq odd; V^T: nq^=4 if d odd) so
//         attn's parity-offset b64 LDS reads assemble operands in true order
//         with zero hot-loop fixup.
// MODE 1: fp32 row-major out [M,N]
// MINW: min blocks/CU (launch_bounds 2nd arg == blocks/CU for 256-thr blocks)
// ---------------------------------------------------------------------------
template <int MODE, int WM, int NBX, int MINW, typename TOUT>
__global__ __launch_bounds__(256, MINW) void gemm_bt(
    const ushort* __restrict__ A, const ushort* __restrict__ W,
    const float* __restrict__ bias, TOUT* __restrict__ out,
    int M, int Nout, int K)
{
    constexpr int BM = 2 * WM * 16;                 // block rows (128 or 64)
    __shared__ __align__(16) ushort As[2][BM * 32];
    __shared__ __align__(16) ushort Bs[2][128 * 32];

    const int tid  = threadIdx.x;
    const int wave = tid >> 6, lane = tid & 63;
    const int quad = lane >> 4, l16 = lane & 15;
    const int wm = wave >> 1, wn = wave & 1;

    // XCD y-slab swizzle: consecutive wgids round-robin XCDs; give XCD x the
    // contiguous lin-range [x*g8, (x+1)*g8) -> contiguous m-rows per XCD.
    const int wg  = blockIdx.x;
    const int g8  = (int)gridDim.x >> 3;
    const int lin = (wg & 7) * g8 + (wg >> 3);
    const int m0 = (lin / NBX) * BM, n0 = (lin % NBX) * 128;

    const int c0 = tid, c1 = tid + 256;
    const ushort* gA0 = A + (size_t)(m0 + (c0 >> 2)) * K + (c0 & 3) * 8;
    const ushort* gA1 = A + (size_t)(m0 + (c1 >> 2)) * K + (c1 & 3) * 8;  // WM==4 only
    const ushort* gB0 = W + (size_t)(n0 + (c0 >> 2)) * K + (c0 & 3) * 8;
    const ushort* gB1 = W + (size_t)(n0 + (c1 >> 2)) * K + (c1 & 3) * 8;

#define STAGE_G(buf, k0)                                                  \
    {                                                                     \
        gl_lds16(gA0 + (k0), &As[buf][(wave * 64) * 8]);                  \
        if (WM == 4) gl_lds16(gA1 + (k0), &As[buf][(wave * 64 + 256) * 8]); \
        gl_lds16(gB0 + (k0), &Bs[buf][(wave * 64) * 8]);                  \
        gl_lds16(gB1 + (k0), &Bs[buf][(wave * 64 + 256) * 8]);            \
    }

    f32x4 acc[WM][4];
#pragma unroll
    for (int i = 0; i < WM; i++)
#pragma unroll
        for (int j = 0; j < 4; j++) acc[i][j] = (f32x4){0.f, 0.f, 0.f, 0.f};

    const int KT = K >> 5;
    STAGE_G(0, 0)

    for (int kt = 0; kt < KT; kt++) {
        const int cur = kt & 1;
        __syncthreads();
        if (kt + 1 < KT) STAGE_G(cur ^ 1, (kt + 1) * 32)

        short8 af[WM], bfr[4];
#pragma unroll
        for (int mt = 0; mt < WM; mt++)
            af[mt] = *(const short8*)&As[cur][(wm * (WM * 16) + mt * 16 + l16) * 32 + quad * 8];
#pragma unroll
        for (int nt = 0; nt < 4; nt++)
            bfr[nt] = *(const short8*)&Bs[cur][(wn * 64 + nt * 16 + l16) * 32 + quad * 8];
#pragma unroll
        for (int mt = 0; mt < WM; mt++)
#pragma unroll
            for (int nt = 0; nt < 4; nt++)
                acc[mt][nt] = MFMA16(af[mt], bfr[nt], acc[mt][nt]);
    }

#pragma unroll
    for (int nt = 0; nt < 4; nt++) {
        const int n = n0 + wn * 64 + nt * 16 + l16;
        const float bv = bias[n];
#pragma unroll
        for (int mt = 0; mt < WM; mt++) {
            const int mBase = m0 + wm * (WM * 16) + mt * 16 + quad * 4;
#pragma unroll
            for (int r = 0; r < 4; r++) {
                const int m = mBase + r;
                float v = acc[mt][nt][r] + bv;
                if (MODE == 0) {
                    const int which = n >> 10, rem = n & 1023;
                    const int h = rem >> 6, d = rem & 63;
                    const int b = m >> 11, nq = m & 2047;
                    const int bh = b * NHEAD + h;
                    if (which == 0) v *= (SCALE * LOG2E);  // fold scale+log2e into Q
                    size_t idx;
                    if (which == 2) {  // V^T [BH][HD][SEQ], half-swap if d odd
                        const int nqs = (d & 1) ? (nq ^ 4) : nq;
                        idx = (size_t)2 * BH * SEQ * HD + ((size_t)bh * HD + d) * SEQ + nqs;
                    } else {           // Q,K: [BH][SEQ][HD]; K half-swap if nq odd
                        const int ds = (which == 1 && (nq & 1)) ? (d ^ 4) : d;
                        idx = (size_t)which * BH * SEQ * HD + ((size_t)bh * SEQ + nq) * HD + ds;
                    }
                    ((ushort*)out)[idx] = f2bf(v);
                } else {
                    ((float*)out)[(size_t)m * Nout + n] = v;
                }
            }
        }
    }
#undef STAGE_G
}

// ---------------------------------------------------------------------------
// Flash attention, 32x32 swapped schedule + 2-way key split (R3 structure)
// with DECONFLICTED LDS reads (R6 variant, zero-fixup):
//   16B-granular DMA swizzle keyed on (row>>1); reads are 2x ds_read_b64 with
//   row-parity address offset -> 16 distinct 8B-groups across 32 lanes ->
//   2-way = free.  Global K/V stored half-preswapped (gemm MODE 0) so
//   operands assemble in true order with no select VALU.
// ---------------------------------------------------------------------------
__global__ __launch_bounds__(512, 4) void attn_kernel(
    const ushort* __restrict__ qkv, ushort* __restrict__ wa)
{
    __shared__ __align__(16) ushort Ks[2][2][64 * 64];   // [half][buf][key][d] swz
    __shared__ __align__(16) ushort Vs[2][2][64 * 64];   // [half][buf][d][key] swz

    const int tid  = threadIdx.x;
    const int wave = tid >> 6, lane = tid & 63;          // wave 0..7
    const int l31  = lane & 31, hb = lane >> 5;
    const int h2 = wave >> 2, w4 = wave & 3;             // key-half, q-subtile

    // XCD swizzle: l%8 == bh%8 -> all 16 q-blocks of a head on one XCD
    const int l = blockIdx.x;
    const int bh = (l & 7) + 8 * (l >> 7);
    const int qi = (l >> 3) & 15;
    const int b = bh >> 4, head = bh & 15;

    const size_t hOff = (size_t)bh * SEQ * HD;
    const ushort* Q  = qkv + hOff;
    const ushort* Kg = qkv + (size_t)BH * SEQ * HD + hOff;
    const ushort* Vt = qkv + (size_t)2 * BH * SEQ * HD + hOff;   // [HD][SEQ]
    const int q0 = qi * 128 + w4 * 32;

    // Q B-frags (pre-scaled by SCALE*LOG2E in GEMM): row q0+l31, d = i*16+hb*8
    short8 qf[4];
#pragma unroll
    for (int i = 0; i < 4; i++)
        qf[i] = *(const short8*)&Q[(size_t)(q0 + l31) * HD + i * 16 + hb * 8];

    f32x16 o0, o1;
#pragma unroll
    for (int r = 0; r < 16; r++) { o0[r] = 0.f; o1[r] = 0.f; }
    f32x4 lacc = (f32x4){0.f, 0.f, 0.f, 0.f};

    // DMA source swizzle, 16B-granular keyed on (row>>1):
    //   physical slot p of row r holds logical chunk p ^ ((r>>1)&7).
    const int rr = lane >> 3;                        // row offset 0..7
    const int cA = (((lane & 7) ^ (rr >> 1)) & 7) * 8;
    const ushort* KgA = Kg + rr * HD + cA;
    const ushort* KgB = Kg + rr * HD + (cA ^ 32);
    const ushort* VtA = Vt + (size_t)rr * SEQ + cA;
    const ushort* VtB = Vt + (size_t)rr * SEQ + (cA ^ 32);

    // per half-quartet: wave w4 stages K rows w4*16..+15 and V^T rows w4*16..+15
#define STAGE(buf, kt)                                                          \
    {                                                                           \
        const size_t kO = (size_t)h2 * 1024 + (size_t)(kt) * 64;                \
        gl_lds16(KgA + (kO + w4 * 16    ) * HD, &Ks[h2][buf][(w4 * 16    ) * 64]); \
        gl_lds16(KgB + (kO + w4 * 16 + 8) * HD, &Ks[h2][buf][(w4 * 16 + 8) * 64]); \
        gl_lds16(VtA + (size_t)(w4 * 16    ) * SEQ + kO, &Vs[h2][buf][(w4 * 16    ) * 64]); \
        gl_lds16(VtB + (size_t)(w4 * 16 + 8) * SEQ + kO, &Vs[h2][buf][(w4 * 16 + 8) * 64]); \
    }

    STAGE(0, 0)

    // read-side: operand (row, chunk c) = b64 pair at row*64 + ((c^sw2)*8) + pb
    // and ^4; content pre-swap makes (h0,h1) true (lo,hi) for both parities.
    const int sw2 = (l31 >> 1) & 7;
    const int pb  = (l31 & 1) * 4;

    for (int kt = 0; kt < NTK; kt++) {
        const int cur = kt & 1;
        __syncthreads();                  // staging(cur) complete (vmcnt drain)
        if (kt + 1 < NTK) STAGE(cur ^ 1, kt + 1)

        const ushort* kb_ = &Ks[h2][cur][0];
        const ushort* vb_ = &Vs[h2][cur][0];

        // S^T = K Q^T : lane holds S[key = 32kb + (r&3)+8(r>>2)+4hb][q = l31]
        f32x16 z0, z1;
#pragma unroll
        for (int r = 0; r < 16; r++) { z0[r] = 0.f; z1[r] = 0.f; }

        __builtin_amdgcn_s_setprio(1);
#pragma unroll
        for (int i = 0; i < 4; i++) {
            const int co = (((2 * i + hb) ^ sw2) * 8) + pb;
            short8 ka0 = ld_op(kb_, (l31     ) * 64 + co);
            short8 ka1 = ld_op(kb_, (32 + l31) * 64 + co);
            z0 = MFMA32(ka0, qf[i], z0);
            z1 = MFMA32(ka1, qf[i], z1);
        }
        __builtin_amdgcn_s_setprio(0);

        // fixed-base softmax numerator + in-register bf16 pack
        unsigned u[2][8];
#pragma unroll
        for (int r = 0; r < 16; r++) {
            const float p0 = __builtin_amdgcn_exp2f(z0[r]);
            const float p1 = __builtin_amdgcn_exp2f(z1[r]);
            z0[r] = p0; z1[r] = p1;
            lacc[r & 3] += p0 + p1;
        }
#pragma unroll
        for (int m = 0; m < 8; m++) {
            unsigned pk;
            asm("v_cvt_pk_bf16_f32 %0, %1, %2"
                : "=v"(pk) : "v"(z0[2*m]), "v"(z0[2*m + 1]));
            u[0][m] = pk;
            asm("v_cvt_pk_bf16_f32 %0, %1, %2"
                : "=v"(pk) : "v"(z1[2*m]), "v"(z1[2*m + 1]));
            u[1][m] = pk;
        }

        // PV: A-frags via permlane32_swap; B = V^T rows (d), k = keys
        __builtin_amdgcn_s_setprio(1);
#pragma unroll
        for (int i = 0; i < 4; i++) {
            const int kb = i >> 1, ii = i & 1;
            uint2v s0 = __builtin_amdgcn_permlane32_swap(
                u[kb][4*ii + 0], u[kb][4*ii + 2], false, false);
            uint2v s1 = __builtin_amdgcn_permlane32_swap(
                u[kb][4*ii + 1], u[kb][4*ii + 3], false, false);
            union { unsigned w[4]; short8 s; } pf;
            pf.w[0] = s0[0]; pf.w[1] = s1[0]; pf.w[2] = s0[1]; pf.w[3] = s1[1];
            const int co = (((2 * i + hb) ^ sw2) * 8) + pb;
            short8 vb0 = ld_op(vb_, (l31     ) * 64 + co);
            short8 vb1 = ld_op(vb_, (32 + l31) * 64 + co);
            o0 = MFMA32(pf.s, vb0, o0);
            o1 = MFMA32(pf.s, vb1, o1);
        }
        __builtin_amdgcn_s_setprio(0);
    }

    // ----- merge the two key-halves (fixed base => purely additive) -----
    __syncthreads();   // all waves done with Ks/Vs; safe to alias scratch

    // scratch aliased onto dead K/V buffers: LDS stays exactly 64KB
    float* Osc = (float*)&Ks[0][0][0];   // [w4][qr 0..31][col 0..63]  (32KB)
    float* Lsc = (float*)&Vs[0][0][0];   // [wave][l31]                 (1KB)

    float lsum = lacc[0] + lacc[1] + lacc[2] + lacc[3];
    lsum += __shfl_xor(lsum, 32);              // combine hb key-subsets
    if (lane < 32) Lsc[wave * 32 + l31] = lsum;

    // half-1 waves dump O partials into scratch
    if (h2 == 1) {
#pragma unroll
        for (int r = 0; r < 16; r++) {
            const int qr = (r & 3) + 8 * (r >> 2) + 4 * hb;
            Osc[w4 * 2048 + qr * 64 + l31]      = o0[r];
            Osc[w4 * 2048 + qr * 64 + 32 + l31] = o1[r];
        }
    }
    __syncthreads();

    if (h2 == 0) {
        const float inv = 1.f / (Lsc[w4 * 32 + l31] + Lsc[(4 + w4) * 32 + l31]);
#pragma unroll
        for (int r = 0; r < 16; r++) {
            const int qr = (r & 3) + 8 * (r >> 2) + 4 * hb;
            const float iv = __shfl(inv, qr);
            const float v0 = o0[r] + Osc[w4 * 2048 + qr * 64 + l31];
            const float v1 = o1[r] + Osc[w4 * 2048 + qr * 64 + 32 + l31];
            ushort* dst = wa + ((size_t)(b * SEQ + q0 + qr)) * DIM + head * HD + l31;
            dst[0]  = f2bf(v0 * iv);
            dst[32] = f2bf(v1 * iv);
        }
    }
#undef STAGE
}

// ---------------------------------------------------------------------------
extern "C" void kernel_launch(void* const* d_in, const int* in_sizes, int n_in,
                              void* d_out, int out_size, void* d_ws, size_t ws_size,
                              hipStream_t stream)
{
    const float* x      = (const float*)d_in[0];
    const float* qkv_w  = (const float*)d_in[1];
    const float* qkv_b  = (const float*)d_in[2];
    const float* proj_w = (const float*)d_in[3];
    const float* proj_b = (const float*)d_in[4];
    float* out = (float*)d_out;

    ushort* xb  = (ushort*)d_ws;
    ushort* qwb = xb  + (size_t)N_X;
    ushort* pwb = qwb + (size_t)N_QW;
    ushort* qkv = pwb + (size_t)N_PW;                 // 3*BH*SEQ*HD
    ushort* wa  = qkv + (size_t)3 * BH * SEQ * HD;    // B*SEQ*DIM

    const int M = BATCH * SEQ;   // 4096
    dim3 blk(256);

    cvt_kernel<<<dim3((N_X / 8 + 255) / 256), blk, 0, stream>>>(
        x, qkv_w, proj_w, xb, qwb, pwb);

    // QKV: 128x128 tiles, 1-D grid 768 (XCD y-slab swizzle), 3 blocks/CU
    gemm_bt<0, 4, 24, 3, ushort><<<dim3(768), blk, 0, stream>>>(
        xb, qwb, qkv_b, qkv, M, 3 * DIM, DIM);

    // attn: 1-D grid 512, 512 threads (8 waves, 2-way key split), XCD-swizzled
    attn_kernel<<<dim3(512), dim3(512), 0, stream>>>(qkv, wa);

    // proj: 64x128 tiles, 1-D grid 512 (XCD y-slab swizzle), 2 blocks/CU
    gemm_bt<1, 2, 8, 2, float><<<dim3(512), blk, 0, stream>>>(
        wa, pwb, proj_b, out, M, DIM, DIM);
}

// Round 9
// 185.962 us; speedup vs baseline: 1.0092x; 1.0092x over previous
//
#include <hip/hip_runtime.h>

// Problem constants
#define BATCH 2
#define SEQ   2048
#define DIM   1024
#define NHEAD 16
#define HD    64
#define BH    (BATCH * NHEAD)   // 32
#define SCALE 0.125f            // 64^-0.5
#define LOG2E 1.44269504f
#define NTK   16                // k-tiles of 64 keys per key-half (1024/64)

typedef __attribute__((ext_vector_type(8))) short short8;
typedef __attribute__((ext_vector_type(4))) float f32x4;
typedef __attribute__((ext_vector_type(16))) float f32x16;
typedef __attribute__((ext_vector_type(2))) unsigned int uint2v;

#define MFMA16(a, b, c) __builtin_amdgcn_mfma_f32_16x16x32_bf16(a, b, c, 0, 0, 0)
#define MFMA32(a, b, c) __builtin_amdgcn_mfma_f32_32x32x16_bf16(a, b, c, 0, 0, 0)

__device__ __forceinline__ ushort f2bf(float f) {
    union { float f; unsigned u; } v;
    v.f = f;
    unsigned r = (v.u + 0x7FFF + ((v.u >> 16) & 1)) >> 16;   // RNE
    return (ushort)r;
}

__device__ __forceinline__ uint4 ld8f_bf16(const float* p) {
    float4 f0 = *(const float4*)p;
    float4 f1 = *(const float4*)(p + 4);
    union { ushort us[8]; uint4 v; } u;
    u.us[0] = f2bf(f0.x); u.us[1] = f2bf(f0.y);
    u.us[2] = f2bf(f0.z); u.us[3] = f2bf(f0.w);
    u.us[4] = f2bf(f1.x); u.us[5] = f2bf(f1.y);
    u.us[6] = f2bf(f1.z); u.us[7] = f2bf(f1.w);
    return u.v;
}

// async global->LDS, 16B/lane: lane i's 16B lands at l + i*16 (l wave-uniform)
__device__ __forceinline__ void gl_lds16(const ushort* g, ushort* l) {
    __builtin_amdgcn_global_load_lds(
        (const __attribute__((address_space(1))) unsigned int*)g,
        (__attribute__((address_space(3))) unsigned int*)l,
        16, 0, 0);
}

// ---------------------------------------------------------------------------
// fp32 -> bf16 bulk convert: x | qkv_w | proj_w
// ---------------------------------------------------------------------------
#define N_X  (BATCH * SEQ * DIM)       // 4194304
#define N_QW (3 * DIM * DIM)           // 3145728
#define N_PW (DIM * DIM)               // 1048576

__global__ __launch_bounds__(256) void cvt_kernel(
    const float* __restrict__ x, const float* __restrict__ qw,
    const float* __restrict__ pw, ushort* __restrict__ xb,
    ushort* __restrict__ qwb, ushort* __restrict__ pwb)
{
    const int i = (blockIdx.x * 256 + threadIdx.x) * 8;
    if (i < N_X)  *(uint4*)(xb  + i) = ld8f_bf16(x  + i);
    if (i < N_QW) *(uint4*)(qwb + i) = ld8f_bf16(qw + i);
    if (i < N_PW) *(uint4*)(pwb + i) = ld8f_bf16(pw + i);
}

// ---------------------------------------------------------------------------
// GEMM: C[M,N] = A[M,K] @ W[N,K]^T + bias[N], A/W bf16, bias fp32.
// 1-D grid with bijective XCD y-slab swizzle (grid%8==0): each XCD owns a
// contiguous m-row slab -> A-panels L2-resident per XCD.
// MODE 0: scatter bf16 -> Q (pre-scaled by SCALE*LOG2E), K as [BH][SEQ][HD];
//         V transposed as [BH][HD][SEQ]   (plain layouts, no pre-swap)
// MODE 1: fp32 row-major out [M,N]
// MINW: min blocks/CU (launch_bounds 2nd arg == blocks/CU for 256-thr blocks)
// ---------------------------------------------------------------------------
template <int MODE, int WM, int NBX, int MINW, typename TOUT>
__global__ __launch_bounds__(256, MINW) void gemm_bt(
    const ushort* __restrict__ A, const ushort* __restrict__ W,
    const float* __restrict__ bias, TOUT* __restrict__ out,
    int M, int Nout, int K)
{
    constexpr int BM = 2 * WM * 16;                 // block rows (128 or 64)
    __shared__ __align__(16) ushort As[2][BM * 32];
    __shared__ __align__(16) ushort Bs[2][128 * 32];

    const int tid  = threadIdx.x;
    const int wave = tid >> 6, lane = tid & 63;
    const int quad = lane >> 4, l16 = lane & 15;
    const int wm = wave >> 1, wn = wave & 1;

    // XCD y-slab swizzle: consecutive wgids round-robin XCDs; give XCD x the
    // contiguous lin-range [x*g8, (x+1)*g8) -> contiguous m-rows per XCD.
    const int wg  = blockIdx.x;
    const int g8  = (int)gridDim.x >> 3;
    const int lin = (wg & 7) * g8 + (wg >> 3);
    const int m0 = (lin / NBX) * BM, n0 = (lin % NBX) * 128;

    const int c0 = tid, c1 = tid + 256;
    const ushort* gA0 = A + (size_t)(m0 + (c0 >> 2)) * K + (c0 & 3) * 8;
    const ushort* gA1 = A + (size_t)(m0 + (c1 >> 2)) * K + (c1 & 3) * 8;  // WM==4 only
    const ushort* gB0 = W + (size_t)(n0 + (c0 >> 2)) * K + (c0 & 3) * 8;
    const ushort* gB1 = W + (size_t)(n0 + (c1 >> 2)) * K + (c1 & 3) * 8;

#define STAGE_G(buf, k0)                                                  \
    {                                                                     \
        gl_lds16(gA0 + (k0), &As[buf][(wave * 64) * 8]);                  \
        if (WM == 4) gl_lds16(gA1 + (k0), &As[buf][(wave * 64 + 256) * 8]); \
        gl_lds16(gB0 + (k0), &Bs[buf][(wave * 64) * 8]);                  \
        gl_lds16(gB1 + (k0), &Bs[buf][(wave * 64 + 256) * 8]);            \
    }

    f32x4 acc[WM][4];
#pragma unroll
    for (int i = 0; i < WM; i++)
#pragma unroll
        for (int j = 0; j < 4; j++) acc[i][j] = (f32x4){0.f, 0.f, 0.f, 0.f};

    const int KT = K >> 5;
    STAGE_G(0, 0)

    for (int kt = 0; kt < KT; kt++) {
        const int cur = kt & 1;
        __syncthreads();
        if (kt + 1 < KT) STAGE_G(cur ^ 1, (kt + 1) * 32)

        short8 af[WM], bfr[4];
#pragma unroll
        for (int mt = 0; mt < WM; mt++)
            af[mt] = *(const short8*)&As[cur][(wm * (WM * 16) + mt * 16 + l16) * 32 + quad * 8];
#pragma unroll
        for (int nt = 0; nt < 4; nt++)
            bfr[nt] = *(const short8*)&Bs[cur][(wn * 64 + nt * 16 + l16) * 32 + quad * 8];
#pragma unroll
        for (int mt = 0; mt < WM; mt++)
#pragma unroll
            for (int nt = 0; nt < 4; nt++)
                acc[mt][nt] = MFMA16(af[mt], bfr[nt], acc[mt][nt]);
    }

#pragma unroll
    for (int nt = 0; nt < 4; nt++) {
        const int n = n0 + wn * 64 + nt * 16 + l16;
        const float bv = bias[n];
#pragma unroll
        for (int mt = 0; mt < WM; mt++) {
            const int mBase = m0 + wm * (WM * 16) + mt * 16 + quad * 4;
#pragma unroll
            for (int r = 0; r < 4; r++) {
                const int m = mBase + r;
                float v = acc[mt][nt][r] + bv;
                if (MODE == 0) {
                    const int which = n >> 10, rem = n & 1023;
                    const int h = rem >> 6, d = rem & 63;
                    const int b = m >> 11, nq = m & 2047;
                    const int bh = b * NHEAD + h;
                    if (which == 0) v *= (SCALE * LOG2E);  // fold scale+log2e into Q
                    size_t idx;
                    if (which == 2)   // V transposed: [BH][HD][SEQ]
                        idx = (size_t)2 * BH * SEQ * HD + ((size_t)bh * HD + d) * SEQ + nq;
                    else              // Q,K: [BH][SEQ][HD]
                        idx = (size_t)which * BH * SEQ * HD + ((size_t)bh * SEQ + nq) * HD + d;
                    ((ushort*)out)[idx] = f2bf(v);
                } else {
                    ((float*)out)[(size_t)m * Nout + n] = v;
                }
            }
        }
    }
#undef STAGE_G
}

// ---------------------------------------------------------------------------
// Flash attention, 32x32 swapped schedule + in-block 2-way KEY SPLIT
// (R3-exact restore -- best measured attn at 47.0us):
//   512 threads = 8 waves. Waves 0-3 (h2=0): keys 0..1023; waves 4-7 (h2=1):
//   keys 1024..2047. Each wave: 32 q-rows (w4 = wave&3). 64-key k-tiles,
//   double-buffered per half. LDS exactly 64KB; merge scratch ALIASED onto
//   the dead K/V buffers. Fixed-base softmax => halves merge additively.
//   b128 LDS reads with (row&7) 16B-XOR swizzle (4-way conflict accepted:
//   measured cheaper than b64-deconflicted variants, R3 vs R7/R8).
// ---------------------------------------------------------------------------
__global__ __launch_bounds__(512, 4) void attn_kernel(
    const ushort* __restrict__ qkv, ushort* __restrict__ wa)
{
    __shared__ __align__(16) ushort Ks[2][2][64 * 64];   // [half][buf][key][d] swz
    __shared__ __align__(16) ushort Vs[2][2][64 * 64];   // [half][buf][d][key] swz

    const int tid  = threadIdx.x;
    const int wave = tid >> 6, lane = tid & 63;          // wave 0..7
    const int l31  = lane & 31, hb = lane >> 5;
    const int h2 = wave >> 2, w4 = wave & 3;             // key-half, q-subtile

    // XCD swizzle: l%8 == bh%8 -> all 16 q-blocks of a head on one XCD
    const int l = blockIdx.x;
    const int bh = (l & 7) + 8 * (l >> 7);
    const int qi = (l >> 3) & 15;
    const int b = bh >> 4, head = bh & 15;

    const size_t hOff = (size_t)bh * SEQ * HD;
    const ushort* Q  = qkv + hOff;
    const ushort* Kg = qkv + (size_t)BH * SEQ * HD + hOff;
    const ushort* Vt = qkv + (size_t)2 * BH * SEQ * HD + hOff;   // [HD][SEQ]
    const int q0 = qi * 128 + w4 * 32;

    // Q B-frags (pre-scaled by SCALE*LOG2E in GEMM): row q0+l31, d = i*16+hb*8
    short8 qf[4];
#pragma unroll
    for (int i = 0; i < 4; i++)
        qf[i] = *(const short8*)&Q[(size_t)(q0 + l31) * HD + i * 16 + hb * 8];

    f32x16 o0, o1;
#pragma unroll
    for (int r = 0; r < 16; r++) { o0[r] = 0.f; o1[r] = 0.f; }
    f32x4 lacc = (f32x4){0.f, 0.f, 0.f, 0.f};

    // DMA source swizzle: chunk stored at physical p = c ^ (row & 7)
    const int rr = lane >> 3;
    const int cc = ((lane & 7) ^ rr) * 8;
    const ushort* KgL = Kg + rr * HD + cc;
    const ushort* VtL = Vt + (size_t)rr * SEQ + cc;

    // per half-quartet: wave w4 stages K rows w4*16..+15 and V^T rows w4*16..+15
#define STAGE(buf, kt)                                                          \
    {                                                                           \
        const size_t kO = (size_t)h2 * 1024 + (size_t)(kt) * 64;                \
        gl_lds16(KgL + (kO + w4 * 16    ) * HD, &Ks[h2][buf][(w4 * 16    ) * 64]); \
        gl_lds16(KgL + (kO + w4 * 16 + 8) * HD, &Ks[h2][buf][(w4 * 16 + 8) * 64]); \
        gl_lds16(VtL + (size_t)(w4 * 16    ) * SEQ + kO, &Vs[h2][buf][(w4 * 16    ) * 64]); \
        gl_lds16(VtL + (size_t)(w4 * 16 + 8) * SEQ + kO, &Vs[h2][buf][(w4 * 16 + 8) * 64]); \
    }

    STAGE(0, 0)

    const int swz = l31 & 7;   // (row&7) for rows l31 and 32+l31

    for (int kt = 0; kt < NTK; kt++) {
        const int cur = kt & 1;
        __syncthreads();                  // staging(cur) complete (vmcnt drain)
        if (kt + 1 < NTK) STAGE(cur ^ 1, kt + 1)

        const ushort* kb_ = &Ks[h2][cur][0];
        const ushort* vb_ = &Vs[h2][cur][0];

        // S^T = K Q^T : lane holds S[key = 32kb + (r&3)+8(r>>2)+4hb][q = l31]
        f32x16 z0, z1;
#pragma unroll
        for (int r = 0; r < 16; r++) { z0[r] = 0.f; z1[r] = 0.f; }

        __builtin_amdgcn_s_setprio(1);
#pragma unroll
        for (int i = 0; i < 4; i++) {
            short8 ka0 = *(const short8*)&kb_[(l31     ) * 64 + (((2*i + hb) ^ swz) * 8)];
            short8 ka1 = *(const short8*)&kb_[(32 + l31) * 64 + (((2*i + hb) ^ swz) * 8)];
            z0 = MFMA32(ka0, qf[i], z0);
            z1 = MFMA32(ka1, qf[i], z1);
        }
        __builtin_amdgcn_s_setprio(0);

        // fixed-base softmax numerator + in-register bf16 pack
        unsigned u[2][8];
#pragma unroll
        for (int r = 0; r < 16; r++) {
            const float p0 = __builtin_amdgcn_exp2f(z0[r]);
            const float p1 = __builtin_amdgcn_exp2f(z1[r]);
            z0[r] = p0; z1[r] = p1;
            lacc[r & 3] += p0 + p1;
        }
#pragma unroll
        for (int m = 0; m < 8; m++) {
            unsigned pk;
            asm("v_cvt_pk_bf16_f32 %0, %1, %2"
                : "=v"(pk) : "v"(z0[2*m]), "v"(z0[2*m + 1]));
            u[0][m] = pk;
            asm("v_cvt_pk_bf16_f32 %0, %1, %2"
                : "=v"(pk) : "v"(z1[2*m]), "v"(z1[2*m + 1]));
            u[1][m] = pk;
        }

        // PV: A-frags via permlane32_swap; B = V^T rows (d), k = keys
        __builtin_amdgcn_s_setprio(1);
#pragma unroll
        for (int i = 0; i < 4; i++) {
            const int kb = i >> 1, ii = i & 1;
            uint2v s0 = __builtin_amdgcn_permlane32_swap(
                u[kb][4*ii + 0], u[kb][4*ii + 2], false, false);
            uint2v s1 = __builtin_amdgcn_permlane32_swap(
                u[kb][4*ii + 1], u[kb][4*ii + 3], false, false);
            union { unsigned w[4]; short8 s; } pf;
            pf.w[0] = s0[0]; pf.w[1] = s1[0]; pf.w[2] = s0[1]; pf.w[3] = s1[1];
            short8 vb0 = *(const short8*)&vb_[(l31     ) * 64 + (((2*i + hb) ^ swz) * 8)];
            short8 vb1 = *(const short8*)&vb_[(32 + l31) * 64 + (((2*i + hb) ^ swz) * 8)];
            o0 = MFMA32(pf.s, vb0, o0);
            o1 = MFMA32(pf.s, vb1, o1);
        }
        __builtin_amdgcn_s_setprio(0);
    }

    // ----- merge the two key-halves (fixed base => purely additive) -----
    __syncthreads();   // all waves done with Ks/Vs; safe to alias scratch

    // scratch aliased onto dead K/V buffers: LDS stays exactly 64KB
    float* Osc = (float*)&Ks[0][0][0];   // [w4][qr 0..31][col 0..63]  (32KB)
    float* Lsc = (float*)&Vs[0][0][0];   // [wave][l31]                 (1KB)

    float lsum = lacc[0] + lacc[1] + lacc[2] + lacc[3];
    lsum += __shfl_xor(lsum, 32);              // combine hb key-subsets
    if (lane < 32) Lsc[wave * 32 + l31] = lsum;

    // half-1 waves dump O partials into scratch
    if (h2 == 1) {
#pragma unroll
        for (int r = 0; r < 16; r++) {
            const int qr = (r & 3) + 8 * (r >> 2) + 4 * hb;
            Osc[w4 * 2048 + qr * 64 + l31]      = o0[r];
            Osc[w4 * 2048 + qr * 64 + 32 + l31] = o1[r];
        }
    }
    __syncthreads();

    if (h2 == 0) {
        const float inv = 1.f / (Lsc[w4 * 32 + l31] + Lsc[(4 + w4) * 32 + l31]);
#pragma unroll
        for (int r = 0; r < 16; r++) {
            const int qr = (r & 3) + 8 * (r >> 2) + 4 * hb;
            const float iv = __shfl(inv, qr);
            const float v0 = o0[r] + Osc[w4 * 2048 + qr * 64 + l31];
            const float v1 = o1[r] + Osc[w4 * 2048 + qr * 64 + 32 + l31];
            ushort* dst = wa + ((size_t)(b * SEQ + q0 + qr)) * DIM + head * HD + l31;
            dst[0]  = f2bf(v0 * iv);
            dst[32] = f2bf(v1 * iv);
        }
    }
#undef STAGE
}

// ---------------------------------------------------------------------------
extern "C" void kernel_launch(void* const* d_in, const int* in_sizes, int n_in,
                              void* d_out, int out_size, void* d_ws, size_t ws_size,
                              hipStream_t stream)
{
    const float* x      = (const float*)d_in[0];
    const float* qkv_w  = (const float*)d_in[1];
    const float* qkv_b  = (const float*)d_in[2];
    const float* proj_w = (const float*)d_in[3];
    const float* proj_b = (const float*)d_in[4];
    float* out = (float*)d_out;

    ushort* xb  = (ushort*)d_ws;
    ushort* qwb = xb  + (size_t)N_X;
    ushort* pwb = qwb + (size_t)N_QW;
    ushort* qkv = pwb + (size_t)N_PW;                 // 3*BH*SEQ*HD
    ushort* wa  = qkv + (size_t)3 * BH * SEQ * HD;    // B*SEQ*DIM

    const int M = BATCH * SEQ;   // 4096
    dim3 blk(256);

    cvt_kernel<<<dim3((N_X / 8 + 255) / 256), blk, 0, stream>>>(
        x, qkv_w, proj_w, xb, qwb, pwb);

    // QKV: 128x128 tiles, 1-D grid 768 (XCD y-slab swizzle), 3 blocks/CU
    gemm_bt<0, 4, 24, 3, ushort><<<dim3(768), blk, 0, stream>>>(
        xb, qwb, qkv_b, qkv, M, 3 * DIM, DIM);

    // attn: 1-D grid 512, 512 threads (8 waves, 2-way key split), XCD-swizzled
    attn_kernel<<<dim3(512), dim3(512), 0, stream>>>(qkv, wa);

    // proj: 64x128 tiles, 1-D grid 512 (XCD y-slab swizzle), 2 blocks/CU
    gemm_bt<1, 2, 8, 2, float><<<dim3(512), blk, 0, stream>>>(
        wa, pwb, proj_b, out, M, DIM, DIM);
}

// Round 10
// 183.341 us; speedup vs baseline: 1.0236x; 1.0143x over previous
//
#include <hip/hip_runtime.h>

// Problem constants
#define BATCH 2
#define SEQ   2048
#define DIM   1024
#define NHEAD 16
#define HD    64
#define BH    (BATCH * NHEAD)   // 32
#define SCALE 0.125f            // 64^-0.5
#define LOG2E 1.44269504f
#define NTK   16                // k-tiles of 64 keys per key-half (1024/64)

typedef __attribute__((ext_vector_type(8))) short short8;
typedef __attribute__((ext_vector_type(4))) float f32x4;
typedef __attribute__((ext_vector_type(16))) float f32x16;
typedef __attribute__((ext_vector_type(2))) unsigned int uint2v;

#define MFMA16(a, b, c) __builtin_amdgcn_mfma_f32_16x16x32_bf16(a, b, c, 0, 0, 0)
#define MFMA32(a, b, c) __builtin_amdgcn_mfma_f32_32x32x16_bf16(a, b, c, 0, 0, 0)

__device__ __forceinline__ ushort f2bf(float f) {
    union { float f; unsigned u; } v;
    v.f = f;
    unsigned r = (v.u + 0x7FFF + ((v.u >> 16) & 1)) >> 16;   // RNE
    return (ushort)r;
}

__device__ __forceinline__ uint4 ld8f_bf16(const float* p) {
    float4 f0 = *(const float4*)p;
    float4 f1 = *(const float4*)(p + 4);
    union { ushort us[8]; uint4 v; } u;
    u.us[0] = f2bf(f0.x); u.us[1] = f2bf(f0.y);
    u.us[2] = f2bf(f0.z); u.us[3] = f2bf(f0.w);
    u.us[4] = f2bf(f1.x); u.us[5] = f2bf(f1.y);
    u.us[6] = f2bf(f1.z); u.us[7] = f2bf(f1.w);
    return u.v;
}

// async global->LDS, 16B/lane: lane i's 16B lands at l + i*16 (l wave-uniform)
__device__ __forceinline__ void gl_lds16(const ushort* g, ushort* l) {
    __builtin_amdgcn_global_load_lds(
        (const __attribute__((address_space(1))) unsigned int*)g,
        (__attribute__((address_space(3))) unsigned int*)l,
        16, 0, 0);
}

// ---------------------------------------------------------------------------
// fp32 -> bf16 bulk convert: x | qkv_w | proj_w
// ---------------------------------------------------------------------------
#define N_X  (BATCH * SEQ * DIM)       // 4194304
#define N_QW (3 * DIM * DIM)           // 3145728
#define N_PW (DIM * DIM)               // 1048576

__global__ __launch_bounds__(256) void cvt_kernel(
    const float* __restrict__ x, const float* __restrict__ qw,
    const float* __restrict__ pw, ushort* __restrict__ xb,
    ushort* __restrict__ qwb, ushort* __restrict__ pwb)
{
    const int i = (blockIdx.x * 256 + threadIdx.x) * 8;
    if (i < N_X)  *(uint4*)(xb  + i) = ld8f_bf16(x  + i);
    if (i < N_QW) *(uint4*)(qwb + i) = ld8f_bf16(qw + i);
    if (i < N_PW) *(uint4*)(pwb + i) = ld8f_bf16(pw + i);
}

// ---------------------------------------------------------------------------
// GEMM: C[M,N] = A[M,K] @ W[N,K]^T + bias[N], A/W bf16, bias fp32.
// 1-D grid with bijective XCD y-slab swizzle (grid%8==0): each XCD owns a
// contiguous m-row slab -> A-panels L2-resident per XCD.
// MODE 0: scatter bf16 -> Q (pre-scaled by SCALE*LOG2E), K as [BH][SEQ][HD];
//         V transposed as [BH][HD][SEQ].  V^T stores PACKED: the 4 r-values
//         are contiguous in nq -> one 8B store (full 32B sectors per wave
//         store-instr; kills the 3.4x WRITE_SIZE RMW amplification of 2B
//         scattered stores seen in R6 counters).
// MODE 1: fp32 row-major out [M,N]
// MINW: min blocks/CU (launch_bounds 2nd arg == blocks/CU for 256-thr blocks)
// ---------------------------------------------------------------------------
template <int MODE, int WM, int NBX, int MINW, typename TOUT>
__global__ __launch_bounds__(256, MINW) void gemm_bt(
    const ushort* __restrict__ A, const ushort* __restrict__ W,
    const float* __restrict__ bias, TOUT* __restrict__ out,
    int M, int Nout, int K)
{
    constexpr int BM = 2 * WM * 16;                 // block rows (128 or 64)
    __shared__ __align__(16) ushort As[2][BM * 32];
    __shared__ __align__(16) ushort Bs[2][128 * 32];

    const int tid  = threadIdx.x;
    const int wave = tid >> 6, lane = tid & 63;
    const int quad = lane >> 4, l16 = lane & 15;
    const int wm = wave >> 1, wn = wave & 1;

    // XCD y-slab swizzle: consecutive wgids round-robin XCDs; give XCD x the
    // contiguous lin-range [x*g8, (x+1)*g8) -> contiguous m-rows per XCD.
    const int wg  = blockIdx.x;
    const int g8  = (int)gridDim.x >> 3;
    const int lin = (wg & 7) * g8 + (wg >> 3);
    const int m0 = (lin / NBX) * BM, n0 = (lin % NBX) * 128;

    const int c0 = tid, c1 = tid + 256;
    const ushort* gA0 = A + (size_t)(m0 + (c0 >> 2)) * K + (c0 & 3) * 8;
    const ushort* gA1 = A + (size_t)(m0 + (c1 >> 2)) * K + (c1 & 3) * 8;  // WM==4 only
    const ushort* gB0 = W + (size_t)(n0 + (c0 >> 2)) * K + (c0 & 3) * 8;
    const ushort* gB1 = W + (size_t)(n0 + (c1 >> 2)) * K + (c1 & 3) * 8;

#define STAGE_G(buf, k0)                                                  \
    {                                                                     \
        gl_lds16(gA0 + (k0), &As[buf][(wave * 64) * 8]);                  \
        if (WM == 4) gl_lds16(gA1 + (k0), &As[buf][(wave * 64 + 256) * 8]); \
        gl_lds16(gB0 + (k0), &Bs[buf][(wave * 64) * 8]);                  \
        gl_lds16(gB1 + (k0), &Bs[buf][(wave * 64 + 256) * 8]);            \
    }

    f32x4 acc[WM][4];
#pragma unroll
    for (int i = 0; i < WM; i++)
#pragma unroll
        for (int j = 0; j < 4; j++) acc[i][j] = (f32x4){0.f, 0.f, 0.f, 0.f};

    const int KT = K >> 5;                 // always even (K multiple of 64)
    STAGE_G(0, 0)

#pragma unroll 2
    for (int kt = 0; kt < KT; kt++) {
        const int cur = kt & 1;
        __syncthreads();
        if (kt + 1 < KT) STAGE_G(cur ^ 1, (kt + 1) * 32)

        short8 af[WM], bfr[4];
#pragma unroll
        for (int mt = 0; mt < WM; mt++)
            af[mt] = *(const short8*)&As[cur][(wm * (WM * 16) + mt * 16 + l16) * 32 + quad * 8];
#pragma unroll
        for (int nt = 0; nt < 4; nt++)
            bfr[nt] = *(const short8*)&Bs[cur][(wn * 64 + nt * 16 + l16) * 32 + quad * 8];
#pragma unroll
        for (int mt = 0; mt < WM; mt++)
#pragma unroll
            for (int nt = 0; nt < 4; nt++)
                acc[mt][nt] = MFMA16(af[mt], bfr[nt], acc[mt][nt]);
    }

#pragma unroll
    for (int nt = 0; nt < 4; nt++) {
        const int n = n0 + wn * 64 + nt * 16 + l16;
        const float bv = bias[n];
#pragma unroll
        for (int mt = 0; mt < WM; mt++) {
            const int mBase = m0 + wm * (WM * 16) + mt * 16 + quad * 4;
            if (MODE == 0) {
                const int which = n >> 10, rem = n & 1023;
                const int h = rem >> 6, d = rem & 63;
                const int bb = mBase >> 11, nq = mBase & 2047;   // const over r
                const int bh = bb * NHEAD + h;
                if (which == 2) {
                    // V^T [BH][HD][SEQ]: 4 r-values contiguous in nq -> 8B store
                    union { ushort us[4]; unsigned long long u64; } pk;
#pragma unroll
                    for (int r = 0; r < 4; r++) pk.us[r] = f2bf(acc[mt][nt][r] + bv);
                    *(unsigned long long*)((ushort*)out +
                        (size_t)2 * BH * SEQ * HD + ((size_t)bh * HD + d) * SEQ + nq)
                        = pk.u64;
                } else {
#pragma unroll
                    for (int r = 0; r < 4; r++) {
                        float v = acc[mt][nt][r] + bv;
                        if (which == 0) v *= (SCALE * LOG2E);
                        ((ushort*)out)[(size_t)which * BH * SEQ * HD +
                                       ((size_t)bh * SEQ + nq + r) * HD + d] = f2bf(v);
                    }
                }
            } else {
#pragma unroll
                for (int r = 0; r < 4; r++)
                    ((float*)out)[(size_t)(mBase + r) * Nout + n] = acc[mt][nt][r] + bv;
            }
        }
    }
#undef STAGE_G
}

// ---------------------------------------------------------------------------
// Flash attention, 32x32 swapped schedule + in-block 2-way KEY SPLIT
// (R3-exact, best measured attn at 47.0us):
//   512 threads = 8 waves. Waves 0-3 (h2=0): keys 0..1023; waves 4-7 (h2=1):
//   keys 1024..2047. Each wave: 32 q-rows (w4 = wave&3). 64-key k-tiles,
//   double-buffered per half. LDS exactly 64KB; merge scratch ALIASED onto
//   the dead K/V buffers. Fixed-base softmax => halves merge additively.
//   b128 LDS reads with (row&7) 16B-XOR swizzle (4-way conflict accepted:
//   measured cheaper than b64-deconflicted variants, R3 vs R7/R8).
// ---------------------------------------------------------------------------
__global__ __launch_bounds__(512, 4) void attn_kernel(
    const ushort* __restrict__ qkv, ushort* __restrict__ wa)
{
    __shared__ __align__(16) ushort Ks[2][2][64 * 64];   // [half][buf][key][d] swz
    __shared__ __align__(16) ushort Vs[2][2][64 * 64];   // [half][buf][d][key] swz

    const int tid  = threadIdx.x;
    const int wave = tid >> 6, lane = tid & 63;          // wave 0..7
    const int l31  = lane & 31, hb = lane >> 5;
    const int h2 = wave >> 2, w4 = wave & 3;             // key-half, q-subtile

    // XCD swizzle: l%8 == bh%8 -> all 16 q-blocks of a head on one XCD
    const int l = blockIdx.x;
    const int bh = (l & 7) + 8 * (l >> 7);
    const int qi = (l >> 3) & 15;
    const int b = bh >> 4, head = bh & 15;

    const size_t hOff = (size_t)bh * SEQ * HD;
    const ushort* Q  = qkv + hOff;
    const ushort* Kg = qkv + (size_t)BH * SEQ * HD + hOff;
    const ushort* Vt = qkv + (size_t)2 * BH * SEQ * HD + hOff;   // [HD][SEQ]
    const int q0 = qi * 128 + w4 * 32;

    // Q B-frags (pre-scaled by SCALE*LOG2E in GEMM): row q0+l31, d = i*16+hb*8
    short8 qf[4];
#pragma unroll
    for (int i = 0; i < 4; i++)
        qf[i] = *(const short8*)&Q[(size_t)(q0 + l31) * HD + i * 16 + hb * 8];

    f32x16 o0, o1;
#pragma unroll
    for (int r = 0; r < 16; r++) { o0[r] = 0.f; o1[r] = 0.f; }
    f32x4 lacc = (f32x4){0.f, 0.f, 0.f, 0.f};

    // DMA source swizzle: chunk stored at physical p = c ^ (row & 7)
    const int rr = lane >> 3;
    const int cc = ((lane & 7) ^ rr) * 8;
    const ushort* KgL = Kg + rr * HD + cc;
    const ushort* VtL = Vt + (size_t)rr * SEQ + cc;

    // per half-quartet: wave w4 stages K rows w4*16..+15 and V^T rows w4*16..+15
#define STAGE(buf, kt)                                                          \
    {                                                                           \
        const size_t kO = (size_t)h2 * 1024 + (size_t)(kt) * 64;                \
        gl_lds16(KgL + (kO + w4 * 16    ) * HD, &Ks[h2][buf][(w4 * 16    ) * 64]); \
        gl_lds16(KgL + (kO + w4 * 16 + 8) * HD, &Ks[h2][buf][(w4 * 16 + 8) * 64]); \
        gl_lds16(VtL + (size_t)(w4 * 16    ) * SEQ + kO, &Vs[h2][buf][(w4 * 16    ) * 64]); \
        gl_lds16(VtL + (size_t)(w4 * 16 + 8) * SEQ + kO, &Vs[h2][buf][(w4 * 16 + 8) * 64]); \
    }

    STAGE(0, 0)

    const int swz = l31 & 7;   // (row&7) for rows l31 and 32+l31

    for (int kt = 0; kt < NTK; kt++) {
        const int cur = kt & 1;
        __syncthreads();                  // staging(cur) complete (vmcnt drain)
        if (kt + 1 < NTK) STAGE(cur ^ 1, kt + 1)

        const ushort* kb_ = &Ks[h2][cur][0];
        const ushort* vb_ = &Vs[h2][cur][0];

        // S^T = K Q^T : lane holds S[key = 32kb + (r&3)+8(r>>2)+4hb][q = l31]
        f32x16 z0, z1;
#pragma unroll
        for (int r = 0; r < 16; r++) { z0[r] = 0.f; z1[r] = 0.f; }

        __builtin_amdgcn_s_setprio(1);
#pragma unroll
        for (int i = 0; i < 4; i++) {
            short8 ka0 = *(const short8*)&kb_[(l31     ) * 64 + (((2*i + hb) ^ swz) * 8)];
            short8 ka1 = *(const short8*)&kb_[(32 + l31) * 64 + (((2*i + hb) ^ swz) * 8)];
            z0 = MFMA32(ka0, qf[i], z0);
            z1 = MFMA32(ka1, qf[i], z1);
        }
        __builtin_amdgcn_s_setprio(0);

        // fixed-base softmax numerator + in-register bf16 pack
        unsigned u[2][8];
#pragma unroll
        for (int r = 0; r < 16; r++) {
            const float p0 = __builtin_amdgcn_exp2f(z0[r]);
            const float p1 = __builtin_amdgcn_exp2f(z1[r]);
            z0[r] = p0; z1[r] = p1;
            lacc[r & 3] += p0 + p1;
        }
#pragma unroll
        for (int m = 0; m < 8; m++) {
            unsigned pk;
            asm("v_cvt_pk_bf16_f32 %0, %1, %2"
                : "=v"(pk) : "v"(z0[2*m]), "v"(z0[2*m + 1]));
            u[0][m] = pk;
            asm("v_cvt_pk_bf16_f32 %0, %1, %2"
                : "=v"(pk) : "v"(z1[2*m]), "v"(z1[2*m + 1]));
            u[1][m] = pk;
        }

        // PV: A-frags via permlane32_swap; B = V^T rows (d), k = keys
        __builtin_amdgcn_s_setprio(1);
#pragma unroll
        for (int i = 0; i < 4; i++) {
            const int kb = i >> 1, ii = i & 1;
            uint2v s0 = __builtin_amdgcn_permlane32_swap(
                u[kb][4*ii + 0], u[kb][4*ii + 2], false, false);
            uint2v s1 = __builtin_amdgcn_permlane32_swap(
                u[kb][4*ii + 1], u[kb][4*ii + 3], false, false);
            union { unsigned w[4]; short8 s; } pf;
            pf.w[0] = s0[0]; pf.w[1] = s1[0]; pf.w[2] = s0[1]; pf.w[3] = s1[1];
            short8 vb0 = *(const short8*)&vb_[(l31     ) * 64 + (((2*i + hb) ^ swz) * 8)];
            short8 vb1 = *(const short8*)&vb_[(32 + l31) * 64 + (((2*i + hb) ^ swz) * 8)];
            o0 = MFMA32(pf.s, vb0, o0);
            o1 = MFMA32(pf.s, vb1, o1);
        }
        __builtin_amdgcn_s_setprio(0);
    }

    // ----- merge the two key-halves (fixed base => purely additive) -----
    __syncthreads();   // all waves done with Ks/Vs; safe to alias scratch

    // scratch aliased onto dead K/V buffers: LDS stays exactly 64KB
    float* Osc = (float*)&Ks[0][0][0];   // [w4][qr 0..31][col 0..63]  (32KB)
    float* Lsc = (float*)&Vs[0][0][0];   // [wave][l31]                 (1KB)

    float lsum = lacc[0] + lacc[1] + lacc[2] + lacc[3];
    lsum += __shfl_xor(lsum, 32);              // combine hb key-subsets
    if (lane < 32) Lsc[wave * 32 + l31] = lsum;

    // half-1 waves dump O partials into scratch
    if (h2 == 1) {
#pragma unroll
        for (int r = 0; r < 16; r++) {
            const int qr = (r & 3) + 8 * (r >> 2) + 4 * hb;
            Osc[w4 * 2048 + qr * 64 + l31]      = o0[r];
            Osc[w4 * 2048 + qr * 64 + 32 + l31] = o1[r];
        }
    }
    __syncthreads();

    if (h2 == 0) {
        const float inv = 1.f / (Lsc[w4 * 32 + l31] + Lsc[(4 + w4) * 32 + l31]);
#pragma unroll
        for (int r = 0; r < 16; r++) {
            const int qr = (r & 3) + 8 * (r >> 2) + 4 * hb;
            const float iv = __shfl(inv, qr);
            const float v0 = o0[r] + Osc[w4 * 2048 + qr * 64 + l31];
            const float v1 = o1[r] + Osc[w4 * 2048 + qr * 64 + 32 + l31];
            ushort* dst = wa + ((size_t)(b * SEQ + q0 + qr)) * DIM + head * HD + l31;
            dst[0]  = f2bf(v0 * iv);
            dst[32] = f2bf(v1 * iv);
        }
    }
#undef STAGE
}

// ---------------------------------------------------------------------------
extern "C" void kernel_launch(void* const* d_in, const int* in_sizes, int n_in,
                              void* d_out, int out_size, void* d_ws, size_t ws_size,
                              hipStream_t stream)
{
    const float* x      = (const float*)d_in[0];
    const float* qkv_w  = (const float*)d_in[1];
    const float* qkv_b  = (const float*)d_in[2];
    const float* proj_w = (const float*)d_in[3];
    const float* proj_b = (const float*)d_in[4];
    float* out = (float*)d_out;

    ushort* xb  = (ushort*)d_ws;
    ushort* qwb = xb  + (size_t)N_X;
    ushort* pwb = qwb + (size_t)N_QW;
    ushort* qkv = pwb + (size_t)N_PW;                 // 3*BH*SEQ*HD
    ushort* wa  = qkv + (size_t)3 * BH * SEQ * HD;    // B*SEQ*DIM

    const int M = BATCH * SEQ;   // 4096
    dim3 blk(256);

    cvt_kernel<<<dim3((N_X / 8 + 255) / 256), blk, 0, stream>>>(
        x, qkv_w, proj_w, xb, qwb, pwb);

    // QKV: 128x128 tiles, 1-D grid 768 (XCD y-slab swizzle), 3 blocks/CU
    gemm_bt<0, 4, 24, 3, ushort><<<dim3(768), blk, 0, stream>>>(
        xb, qwb, qkv_b, qkv, M, 3 * DIM, DIM);

    // attn: 1-D grid 512, 512 threads (8 waves, 2-way key split), XCD-swizzled
    attn_kernel<<<dim3(512), dim3(512), 0, stream>>>(qkv, wa);

    // proj: 64x128 tiles, 1-D grid 512 (XCD y-slab swizzle), 2 blocks/CU
    gemm_bt<1, 2, 8, 2, float><<<dim3(512), blk, 0, stream>>>(
        wa, pwb, proj_b, out, M, DIM, DIM);
}